// Round 2
// baseline (510.880 us; speedup 1.0000x reference)
//
#include <hip/hip_runtime.h>

#define T 256

// deg[i] = 1.0 (self-loop contribution)
__global__ void k_init_deg(float* __restrict__ deg, int n) {
    int i = blockIdx.x * blockDim.x + threadIdx.x;
    if (i < n) deg[i] = 1.0f;
}

// deg[dst[e]] += 1 over real edges
__global__ void k_count(const int* __restrict__ dst, int e, float* __restrict__ deg) {
    int i = blockIdx.x * blockDim.x + threadIdx.x;
    int base = i * 4;
    if (base + 4 <= e) {
        int4 d = *reinterpret_cast<const int4*>(dst + base);
        atomicAdd(&deg[d.x], 1.0f);
        atomicAdd(&deg[d.y], 1.0f);
        atomicAdd(&deg[d.z], 1.0f);
        atomicAdd(&deg[d.w], 1.0f);
    } else {
        for (int j = base; j < e; ++j) atomicAdd(&deg[dst[j]], 1.0f);
    }
}

// dinv = rsqrt(deg) (in place), p[i] = dinv[i]*x[i], t1 init = p[i] (self-loop term)
__global__ void k_node1(const float* __restrict__ x, float* __restrict__ deg_dinv,
                        float* __restrict__ p, float* __restrict__ t1, int n) {
    int i = blockIdx.x * blockDim.x + threadIdx.x;
    if (i < n) {
        float dv = rsqrtf(deg_dinv[i]);   // deg >= 1 always (self-loops)
        deg_dinv[i] = dv;
        float pi = dv * x[i];
        p[i] = pi;
        t1[i] = pi;
    }
}

// t[dst[e]] += v[src[e]]  (scalar weighted scatter-add)
__global__ void k_edge_scatter(const int* __restrict__ src, const int* __restrict__ dst,
                               const float* __restrict__ v, float* __restrict__ t, int e) {
    int i = blockIdx.x * blockDim.x + threadIdx.x;
    int base = i * 4;
    if (base + 4 <= e) {
        int4 s = *reinterpret_cast<const int4*>(src + base);
        int4 d = *reinterpret_cast<const int4*>(dst + base);
        float vx = v[s.x], vy = v[s.y], vz = v[s.z], vw = v[s.w];
        atomicAdd(&t[d.x], vx);
        atomicAdd(&t[d.y], vy);
        atomicAdd(&t[d.z], vz);
        atomicAdd(&t[d.w], vw);
    } else {
        for (int j = base; j < e; ++j) atomicAdd(&t[dst[j]], v[src[j]]);
    }
}

// u = dinv*t1; h1 = relu(u*W1+b1); h2 = h1 . W2; q = dinv*h2; t2 init = q
__global__ void k_node2(const float* __restrict__ dinv, const float* __restrict__ t1,
                        const float* __restrict__ W1, const float* __restrict__ b1,
                        const float* __restrict__ W2,
                        float* __restrict__ q, float* __restrict__ t2, int n) {
    int i = blockIdx.x * blockDim.x + threadIdx.x;
    if (i < n) {
        float dv = dinv[i];
        float u = dv * t1[i];
        float h2 = 0.0f;
#pragma unroll
        for (int f = 0; f < 16; ++f) {
            float h = fmaxf(fmaf(u, W1[f], b1[f]), 0.0f);
            h2 = fmaf(h, W2[f], h2);
        }
        float qi = dv * h2;
        q[i] = qi;
        t2[i] = qi;
    }
}

// out = dinv*t2 + b2
__global__ void k_out(const float* __restrict__ dinv, const float* __restrict__ t2,
                      const float* __restrict__ b2, float* __restrict__ out, int n) {
    int i = blockIdx.x * blockDim.x + threadIdx.x;
    if (i < n) out[i] = fmaf(dinv[i], t2[i], b2[0]);
}

extern "C" void kernel_launch(void* const* d_in, const int* in_sizes, int n_in,
                              void* d_out, int out_size, void* d_ws, size_t ws_size,
                              hipStream_t stream) {
    // setup_inputs order: x, W1, b1, W2, b2, edge_index
    const float* x  = (const float*)d_in[0];
    const float* W1 = (const float*)d_in[1];
    const float* b1 = (const float*)d_in[2];
    const float* W2 = (const float*)d_in[3];
    const float* b2 = (const float*)d_in[4];
    const int*   ei = (const int*)d_in[5];   // [2, E] int32

    const int n = in_sizes[0];        // 100000 (x is [N,1])
    const int e = in_sizes[5] / 2;    // 3200000
    const int* src = ei;
    const int* dst = ei + e;

    float* deg = (float*)d_ws;        // becomes dinv after k_node1
    float* p   = deg + n;
    float* t1  = p + n;
    float* q   = t1 + n;
    float* t2  = q + n;

    float* out = (float*)d_out;

    const int nb_n = (n + T - 1) / T;
    const int e4   = (e + 3) / 4;     // threads, 4 edges each
    const int nb_e = (e4 + T - 1) / T;

    k_init_deg<<<nb_n, T, 0, stream>>>(deg, n);
    k_count<<<nb_e, T, 0, stream>>>(dst, e, deg);
    k_node1<<<nb_n, T, 0, stream>>>(x, deg, p, t1, n);
    k_edge_scatter<<<nb_e, T, 0, stream>>>(src, dst, p, t1, e);
    k_node2<<<nb_n, T, 0, stream>>>(deg, t1, W1, b1, W2, q, t2, n);
    k_edge_scatter<<<nb_e, T, 0, stream>>>(src, dst, q, t2, e);
    k_out<<<nb_n, T, 0, stream>>>(deg, t2, b2, out, n);
}

// Round 4
// 490.896 us; speedup vs baseline: 1.0407x; 1.0407x over previous
//
#include <hip/hip_runtime.h>

#define T 256

// zero `total` floats, grid-stride, vectorized
__global__ void k_zero(float* __restrict__ c, int total) {
    int nvec = total >> 2;
    float4* c4 = (float4*)c;
    int i = blockIdx.x * blockDim.x + threadIdx.x;
    int stride = gridDim.x * blockDim.x;
    float4 z = {0.f, 0.f, 0.f, 0.f};
    for (int j = i; j < nvec; j += stride) c4[j] = z;
    if (i < (total & 3)) c[(nvec << 2) + i] = 0.f;
}

// degree count into shadow copy (blockIdx & kmask)
__global__ void k_count(const int* __restrict__ dst, int e,
                        float* __restrict__ copies, int n, int kmask) {
    float* c = copies + (size_t)(blockIdx.x & kmask) * n;
    int i = blockIdx.x * blockDim.x + threadIdx.x;
    int base = i * 4;
    if (base + 4 <= e) {
        int4 d = *reinterpret_cast<const int4*>(dst + base);
        unsafeAtomicAdd(&c[d.x], 1.0f);
        unsafeAtomicAdd(&c[d.y], 1.0f);
        unsafeAtomicAdd(&c[d.z], 1.0f);
        unsafeAtomicAdd(&c[d.w], 1.0f);
    } else {
        for (int j = base; j < e; ++j) unsafeAtomicAdd(&c[dst[j]], 1.0f);
    }
}

// t[dst] += v[src] into shadow copy (blockIdx & kmask)
__global__ void k_scatter(const int* __restrict__ src, const int* __restrict__ dst,
                          const float* __restrict__ v,
                          float* __restrict__ copies, int n, int kmask, int e) {
    float* c = copies + (size_t)(blockIdx.x & kmask) * n;
    int i = blockIdx.x * blockDim.x + threadIdx.x;
    int base = i * 4;
    if (base + 4 <= e) {
        int4 s = *reinterpret_cast<const int4*>(src + base);
        int4 d = *reinterpret_cast<const int4*>(dst + base);
        float vx = v[s.x], vy = v[s.y], vz = v[s.z], vw = v[s.w];
        unsafeAtomicAdd(&c[d.x], vx);
        unsafeAtomicAdd(&c[d.y], vy);
        unsafeAtomicAdd(&c[d.z], vz);
        unsafeAtomicAdd(&c[d.w], vw);
    } else {
        for (int j = base; j < e; ++j) unsafeAtomicAdd(&c[dst[j]], v[src[j]]);
    }
}

// deg = 1 + sum(copies); dinv = rsqrt(deg); p = dinv*x; rezero copies
__global__ void k_node1(const float* __restrict__ x, float* __restrict__ copies,
                        float* __restrict__ dinv, float* __restrict__ p, int n, int K) {
    int i = blockIdx.x * blockDim.x + threadIdx.x;
    if (i < n) {
        float s = 1.0f;  // self-loop
        for (int k = 0; k < K; ++k) { s += copies[(size_t)k * n + i]; copies[(size_t)k * n + i] = 0.f; }
        float dv = rsqrtf(s);
        dinv[i] = dv;
        p[i] = dv * x[i];
    }
}

// t1 = p + sum(copies); u = dinv*t1; 16-wide MLP; q = dinv*h2; rezero copies
__global__ void k_node2(const float* __restrict__ dinv, const float* __restrict__ p,
                        float* __restrict__ copies,
                        const float* __restrict__ W1, const float* __restrict__ b1,
                        const float* __restrict__ W2,
                        float* __restrict__ q, int n, int K) {
    int i = blockIdx.x * blockDim.x + threadIdx.x;
    if (i < n) {
        float t1 = p[i];
        for (int k = 0; k < K; ++k) { t1 += copies[(size_t)k * n + i]; copies[(size_t)k * n + i] = 0.f; }
        float dv = dinv[i];
        float u = dv * t1;
        float h2 = 0.0f;
#pragma unroll
        for (int f = 0; f < 16; ++f) {
            float h = fmaxf(fmaf(u, W1[f], b1[f]), 0.0f);
            h2 = fmaf(h, W2[f], h2);
        }
        q[i] = dv * h2;
    }
}

// out = dinv*(q + sum(copies)) + b2
__global__ void k_out(const float* __restrict__ dinv, const float* __restrict__ q,
                      const float* __restrict__ copies,
                      const float* __restrict__ b2, float* __restrict__ out, int n, int K) {
    int i = blockIdx.x * blockDim.x + threadIdx.x;
    if (i < n) {
        float t2 = q[i];
        for (int k = 0; k < K; ++k) t2 += copies[(size_t)k * n + i];
        out[i] = fmaf(dinv[i], t2, b2[0]);
    }
}

extern "C" void kernel_launch(void* const* d_in, const int* in_sizes, int n_in,
                              void* d_out, int out_size, void* d_ws, size_t ws_size,
                              hipStream_t stream) {
    // setup_inputs order: x, W1, b1, W2, b2, edge_index
    const float* x  = (const float*)d_in[0];
    const float* W1 = (const float*)d_in[1];
    const float* b1 = (const float*)d_in[2];
    const float* W2 = (const float*)d_in[3];
    const float* b2 = (const float*)d_in[4];
    const int*   ei = (const int*)d_in[5];   // [2, E] int32

    const int n = in_sizes[0];        // 100000
    const int e = in_sizes[5] / 2;    // 3200000
    const int* src = ei;
    const int* dst = ei + e;

    // workspace layout: dinv(n), p(n), q(n), copies(K*n) — K sized to fit ws_size
    long long avail = (long long)(ws_size / 4) - 3LL * n;
    int K = 1;
    while (K * 2 <= 8 && (long long)(K * 2) * n <= avail) K *= 2;
    const int kmask = K - 1;

    float* dinv   = (float*)d_ws;
    float* p      = dinv + n;
    float* q      = p + n;
    float* copies = q + n;

    float* out = (float*)d_out;

    const int nb_n = (n + T - 1) / T;
    const int e4   = (e + 3) / 4;
    const int nb_e = (e4 + T - 1) / T;
    const int nb_z = min(((K * n / 4) + T - 1) / T, 2048);

    k_zero<<<nb_z, T, 0, stream>>>(copies, K * n);
    k_count<<<nb_e, T, 0, stream>>>(dst, e, copies, n, kmask);
    k_node1<<<nb_n, T, 0, stream>>>(x, copies, dinv, p, n, K);
    k_scatter<<<nb_e, T, 0, stream>>>(src, dst, p, copies, n, kmask, e);
    k_node2<<<nb_n, T, 0, stream>>>(dinv, p, copies, W1, b1, W2, q, n, K);
    k_scatter<<<nb_e, T, 0, stream>>>(src, dst, q, copies, n, kmask, e);
    k_out<<<nb_n, T, 0, stream>>>(dinv, q, copies, b2, out, n, K);
}

// Round 5
// 208.608 us; speedup vs baseline: 2.4490x; 2.3532x over previous
//
#include <hip/hip_runtime.h>

#define T 256
#define CHUNK 16384   // 64 KB static LDS per block; P = ceil(n/CHUNK)

// ======================= LDS-partition path (no global atomics) =======================

// degree histogram: block (p,g) counts dsts in [p*CHUNK, p*CHUNK+CHUNK) over edge slice g
__global__ void k_cnt_part(const int* __restrict__ dst, int e, int G,
                           float* __restrict__ copies, int n) {
    const int g = blockIdx.x % G;
    const int p = blockIdx.x / G;
    __shared__ float lds[CHUNK];
    for (int t = threadIdx.x; t < CHUNK; t += T) lds[t] = 0.f;
    __syncthreads();
    const int lo = p * CHUNK;
    const int nv4 = e >> 2;
    const long s4 = (long)g * nv4 / G;
    const long e4 = (long)(g + 1) * nv4 / G;
    const int4* d4 = (const int4*)dst;
    for (long i = s4 + threadIdx.x; i < e4; i += T) {
        int4 d = d4[i];
        if ((unsigned)(d.x - lo) < (unsigned)CHUNK) atomicAdd(&lds[d.x - lo], 1.f);
        if ((unsigned)(d.y - lo) < (unsigned)CHUNK) atomicAdd(&lds[d.y - lo], 1.f);
        if ((unsigned)(d.z - lo) < (unsigned)CHUNK) atomicAdd(&lds[d.z - lo], 1.f);
        if ((unsigned)(d.w - lo) < (unsigned)CHUNK) atomicAdd(&lds[d.w - lo], 1.f);
    }
    if (g == G - 1) {  // tail edges (e % 4)
        for (int j = (nv4 << 2) + threadIdx.x; j < e; j += T) {
            int d = dst[j];
            if ((unsigned)(d - lo) < (unsigned)CHUNK) atomicAdd(&lds[d - lo], 1.f);
        }
    }
    __syncthreads();
    const int lim = min(CHUNK, n - lo);
    float* outp = copies + (size_t)g * n + lo;
    for (int t = threadIdx.x; t < lim; t += T) outp[t] = lds[t];
}

// weighted scatter: lds[dst-lo] += v[src] over edge slice g, partition p
__global__ void k_sct_part(const int* __restrict__ src, const int* __restrict__ dst,
                           const float* __restrict__ v, int e, int G,
                           float* __restrict__ copies, int n) {
    const int g = blockIdx.x % G;
    const int p = blockIdx.x / G;
    __shared__ float lds[CHUNK];
    for (int t = threadIdx.x; t < CHUNK; t += T) lds[t] = 0.f;
    __syncthreads();
    const int lo = p * CHUNK;
    const int nv4 = e >> 2;
    const long s4 = (long)g * nv4 / G;
    const long e4 = (long)(g + 1) * nv4 / G;
    const int4* d4 = (const int4*)dst;
    const int4* s4p = (const int4*)src;
    for (long i = s4 + threadIdx.x; i < e4; i += T) {
        int4 d = d4[i];
        int4 s = s4p[i];
        if ((unsigned)(d.x - lo) < (unsigned)CHUNK) atomicAdd(&lds[d.x - lo], v[s.x]);
        if ((unsigned)(d.y - lo) < (unsigned)CHUNK) atomicAdd(&lds[d.y - lo], v[s.y]);
        if ((unsigned)(d.z - lo) < (unsigned)CHUNK) atomicAdd(&lds[d.z - lo], v[s.z]);
        if ((unsigned)(d.w - lo) < (unsigned)CHUNK) atomicAdd(&lds[d.w - lo], v[s.w]);
    }
    if (g == G - 1) {
        for (int j = (nv4 << 2) + threadIdx.x; j < e; j += T) {
            int d = dst[j];
            if ((unsigned)(d - lo) < (unsigned)CHUNK) atomicAdd(&lds[d - lo], v[src[j]]);
        }
    }
    __syncthreads();
    const int lim = min(CHUNK, n - lo);
    float* outp = copies + (size_t)g * n + lo;
    for (int t = threadIdx.x; t < lim; t += T) outp[t] = lds[t];
}

// ======================= global-atomic fallback (round-4, known-good) =================

__global__ void k_zero(float* __restrict__ c, int total) {
    int nvec = total >> 2;
    float4* c4 = (float4*)c;
    int i = blockIdx.x * blockDim.x + threadIdx.x;
    int stride = gridDim.x * blockDim.x;
    float4 z = {0.f, 0.f, 0.f, 0.f};
    for (int j = i; j < nvec; j += stride) c4[j] = z;
    if (i < (total & 3)) c[(nvec << 2) + i] = 0.f;
}

__global__ void k_count_atomic(const int* __restrict__ dst, int e,
                               float* __restrict__ copies, int n, int kmask) {
    float* c = copies + (size_t)(blockIdx.x & kmask) * n;
    int i = blockIdx.x * blockDim.x + threadIdx.x;
    int base = i * 4;
    if (base + 4 <= e) {
        int4 d = *reinterpret_cast<const int4*>(dst + base);
        unsafeAtomicAdd(&c[d.x], 1.0f);
        unsafeAtomicAdd(&c[d.y], 1.0f);
        unsafeAtomicAdd(&c[d.z], 1.0f);
        unsafeAtomicAdd(&c[d.w], 1.0f);
    } else {
        for (int j = base; j < e; ++j) unsafeAtomicAdd(&c[dst[j]], 1.0f);
    }
}

__global__ void k_scatter_atomic(const int* __restrict__ src, const int* __restrict__ dst,
                                 const float* __restrict__ v,
                                 float* __restrict__ copies, int n, int kmask, int e) {
    float* c = copies + (size_t)(blockIdx.x & kmask) * n;
    int i = blockIdx.x * blockDim.x + threadIdx.x;
    int base = i * 4;
    if (base + 4 <= e) {
        int4 s = *reinterpret_cast<const int4*>(src + base);
        int4 d = *reinterpret_cast<const int4*>(dst + base);
        float vx = v[s.x], vy = v[s.y], vz = v[s.z], vw = v[s.w];
        unsafeAtomicAdd(&c[d.x], vx);
        unsafeAtomicAdd(&c[d.y], vy);
        unsafeAtomicAdd(&c[d.z], vz);
        unsafeAtomicAdd(&c[d.w], vw);
    } else {
        for (int j = base; j < e; ++j) unsafeAtomicAdd(&c[dst[j]], v[src[j]]);
    }
}

// ======================= node-side combine kernels (shared) ===========================

// deg = 1 + sum(copies); dinv = rsqrt(deg); p = dinv*x; optional rezero
__global__ void k_node1(const float* __restrict__ x, float* __restrict__ copies,
                        float* __restrict__ dinv, float* __restrict__ p,
                        int n, int K, int rz) {
    int i = blockIdx.x * blockDim.x + threadIdx.x;
    if (i < n) {
        float s = 1.0f;  // self-loop
        for (int k = 0; k < K; ++k) {
            s += copies[(size_t)k * n + i];
            if (rz) copies[(size_t)k * n + i] = 0.f;
        }
        float dv = rsqrtf(s);
        dinv[i] = dv;
        p[i] = dv * x[i];
    }
}

// t1 = p + sum(copies); u = dinv*t1; 16-wide MLP; q = dinv*h2; optional rezero
__global__ void k_node2(const float* __restrict__ dinv, const float* __restrict__ p,
                        float* __restrict__ copies,
                        const float* __restrict__ W1, const float* __restrict__ b1,
                        const float* __restrict__ W2,
                        float* __restrict__ q, int n, int K, int rz) {
    int i = blockIdx.x * blockDim.x + threadIdx.x;
    if (i < n) {
        float t1 = p[i];
        for (int k = 0; k < K; ++k) {
            t1 += copies[(size_t)k * n + i];
            if (rz) copies[(size_t)k * n + i] = 0.f;
        }
        float dv = dinv[i];
        float u = dv * t1;
        float h2 = 0.0f;
#pragma unroll
        for (int f = 0; f < 16; ++f) {
            float h = fmaxf(fmaf(u, W1[f], b1[f]), 0.0f);
            h2 = fmaf(h, W2[f], h2);
        }
        q[i] = dv * h2;
    }
}

// out = dinv*(q + sum(copies)) + b2
__global__ void k_out(const float* __restrict__ dinv, const float* __restrict__ q,
                      const float* __restrict__ copies,
                      const float* __restrict__ b2, float* __restrict__ out, int n, int K) {
    int i = blockIdx.x * blockDim.x + threadIdx.x;
    if (i < n) {
        float t2 = q[i];
        for (int k = 0; k < K; ++k) t2 += copies[(size_t)k * n + i];
        out[i] = fmaf(dinv[i], t2, b2[0]);
    }
}

// ======================================================================================

extern "C" void kernel_launch(void* const* d_in, const int* in_sizes, int n_in,
                              void* d_out, int out_size, void* d_ws, size_t ws_size,
                              hipStream_t stream) {
    // setup_inputs order: x, W1, b1, W2, b2, edge_index
    const float* x  = (const float*)d_in[0];
    const float* W1 = (const float*)d_in[1];
    const float* b1 = (const float*)d_in[2];
    const float* W2 = (const float*)d_in[3];
    const float* b2 = (const float*)d_in[4];
    const int*   ei = (const int*)d_in[5];   // [2, E] int32

    const int n = in_sizes[0];        // 100000
    const int e = in_sizes[5] / 2;    // 3200000
    const int* src = ei;
    const int* dst = ei + e;

    // workspace: dinv(n), p(n), q(n), copies(G*n)
    float* dinv   = (float*)d_ws;
    float* p      = dinv + n;
    float* q      = p + n;
    float* copies = q + n;
    float* out    = (float*)d_out;

    long long avail = (long long)(ws_size / 4) - 3LL * n;   // floats for copies
    int G = (int)(avail / n);
    if (G > 64) G = 64;

    const int nb_n = (n + T - 1) / T;

    if (G >= 16) {
        // ---------- LDS-partition path ----------
        const int P = (n + CHUNK - 1) / CHUNK;
        const int nb_part = P * G;
        k_cnt_part<<<nb_part, T, 0, stream>>>(dst, e, G, copies, n);
        k_node1<<<nb_n, T, 0, stream>>>(x, copies, dinv, p, n, G, 0);
        k_sct_part<<<nb_part, T, 0, stream>>>(src, dst, p, e, G, copies, n);
        k_node2<<<nb_n, T, 0, stream>>>(dinv, p, copies, W1, b1, W2, q, n, G, 0);
        k_sct_part<<<nb_part, T, 0, stream>>>(src, dst, q, e, G, copies, n);
        k_out<<<nb_n, T, 0, stream>>>(dinv, q, copies, b2, out, n, G);
    } else {
        // ---------- global-atomic fallback (round-4 behavior) ----------
        int K = 1;
        while (K * 2 <= 8 && (long long)(K * 2) * n <= avail) K *= 2;
        const int kmask = K - 1;
        const int e4   = (e + 3) / 4;
        const int nb_e = (e4 + T - 1) / T;
        const int nb_z = min(((K * n / 4) + T - 1) / T, 2048);

        k_zero<<<nb_z, T, 0, stream>>>(copies, K * n);
        k_count_atomic<<<nb_e, T, 0, stream>>>(dst, e, copies, n, kmask);
        k_node1<<<nb_n, T, 0, stream>>>(x, copies, dinv, p, n, K, 1);
        k_scatter_atomic<<<nb_e, T, 0, stream>>>(src, dst, p, copies, n, kmask, e);
        k_node2<<<nb_n, T, 0, stream>>>(dinv, p, copies, W1, b1, W2, q, n, K, 1);
        k_scatter_atomic<<<nb_e, T, 0, stream>>>(src, dst, q, copies, n, kmask, e);
        k_out<<<nb_n, T, 0, stream>>>(dinv, q, copies, b2, out, n, K);
    }
}

// Round 6
// 177.174 us; speedup vs baseline: 2.8835x; 1.1774x over previous
//
#include <hip/hip_runtime.h>

#define T 256
#define CH 8192          // binned-path chunk: 32 KB LDS, 5 blocks/CU
#define CH2 16384        // fallback (round-5) chunk
#define BB 512           // binning blocks
#define PMAX 16

// ============================ binned path =============================

// per-block histogram of dst partitions (register counters, unrolled)
__global__ void k_binhist(const int* __restrict__ dst, int e,
                          int* __restrict__ blockCnt) {
    const int b = blockIdx.x;
    int cnt[PMAX];
#pragma unroll
    for (int k = 0; k < PMAX; ++k) cnt[k] = 0;
    const int nv4 = e >> 2;
    const long s4 = (long)b * nv4 / BB;
    const long e4 = (long)(b + 1) * nv4 / BB;
    const int4* d4 = (const int4*)dst;
    for (long i = s4 + threadIdx.x; i < e4; i += T) {
        int4 d = d4[i];
        int px = d.x >> 13, py = d.y >> 13, pz = d.z >> 13, pw = d.w >> 13;
#pragma unroll
        for (int k = 0; k < PMAX; ++k)
            cnt[k] += (px == k) + (py == k) + (pz == k) + (pw == k);
    }
    if (b == BB - 1) {
        for (int j = (nv4 << 2) + threadIdx.x; j < e; j += T) {
            int p = dst[j] >> 13;
#pragma unroll
            for (int k = 0; k < PMAX; ++k) cnt[k] += (p == k);
        }
    }
    __shared__ int h[PMAX];
    for (int t = threadIdx.x; t < PMAX; t += T) h[t] = 0;
    __syncthreads();
#pragma unroll
    for (int k = 0; k < PMAX; ++k) {
        int v = cnt[k];
        for (int off = 32; off; off >>= 1) v += __shfl_down(v, off);
        if ((threadIdx.x & 63) == 0 && v) atomicAdd(&h[k], v);
    }
    __syncthreads();
    for (int t = threadIdx.x; t < PMAX; t += T) blockCnt[b * PMAX + t] = h[t];
}

// single block: bin totals -> binStart (exclusive prefix) + cursor init
__global__ void k_prefix(const int* __restrict__ blockCnt, int P,
                         int* __restrict__ cursor, int* __restrict__ binStart) {
    __shared__ int part[256][PMAX];   // 16 KB
    int t = threadIdx.x;
    int loc[PMAX];
#pragma unroll
    for (int k = 0; k < PMAX; ++k) loc[k] = 0;
    for (int b = t; b < BB; b += 256)
#pragma unroll
        for (int k = 0; k < PMAX; ++k) loc[k] += blockCnt[b * PMAX + k];
#pragma unroll
    for (int k = 0; k < PMAX; ++k) part[t][k] = loc[k];
    __syncthreads();
    if (t == 0) {
        int acc = 0;
        for (int p = 0; p < P; ++p) {
            int s = 0;
            for (int u = 0; u < 256; ++u) s += part[u][p];
            binStart[p] = acc; cursor[p] = acc; acc += s;
        }
        binStart[P] = acc;
    }
}

// place packed records: binned[slot] = (src<<13)|localdst
__global__ void k_binplace(const int* __restrict__ src, const int* __restrict__ dst,
                           int e, int P, const int* __restrict__ blockCnt,
                           int* __restrict__ cursor, unsigned* __restrict__ binned) {
    const int b = blockIdx.x;
    __shared__ int lbase[PMAX];
    __shared__ int lcur[PMAX];
    if (threadIdx.x < PMAX) {
        int base = 0;
        if (threadIdx.x < P) {
            int c = blockCnt[b * PMAX + threadIdx.x];
            base = atomicAdd(&cursor[threadIdx.x], c);
        }
        lbase[threadIdx.x] = base;
        lcur[threadIdx.x] = 0;
    }
    __syncthreads();
    const int nv4 = e >> 2;
    const long s4 = (long)b * nv4 / BB;
    const long e4 = (long)(b + 1) * nv4 / BB;
    const int4* d4 = (const int4*)dst;
    const int4* s4p = (const int4*)src;
    for (long i = s4 + threadIdx.x; i < e4; i += T) {
        int4 d = d4[i];
        int4 s = s4p[i];
        int pb, off;
        pb = d.x >> 13; off = atomicAdd(&lcur[pb], 1);
        binned[lbase[pb] + off] = ((unsigned)s.x << 13) | (unsigned)(d.x & (CH - 1));
        pb = d.y >> 13; off = atomicAdd(&lcur[pb], 1);
        binned[lbase[pb] + off] = ((unsigned)s.y << 13) | (unsigned)(d.y & (CH - 1));
        pb = d.z >> 13; off = atomicAdd(&lcur[pb], 1);
        binned[lbase[pb] + off] = ((unsigned)s.z << 13) | (unsigned)(d.z & (CH - 1));
        pb = d.w >> 13; off = atomicAdd(&lcur[pb], 1);
        binned[lbase[pb] + off] = ((unsigned)s.w << 13) | (unsigned)(d.w & (CH - 1));
    }
    if (b == BB - 1) {
        for (int j = (nv4 << 2) + threadIdx.x; j < e; j += T) {
            int d = dst[j];
            int pb = d >> 13;
            int off = atomicAdd(&lcur[pb], 1);
            binned[lbase[pb] + off] = ((unsigned)src[j] << 13) | (unsigned)(d & (CH - 1));
        }
    }
}

// degree count over bin p, slice g
__global__ void k_cnt_bin(const unsigned* __restrict__ binned, const int* __restrict__ binStart,
                          int G, float* __restrict__ copies, int n) {
    const int g = blockIdx.x % G;
    const int p = blockIdx.x / G;
    __shared__ float lds[CH];
    for (int t = threadIdx.x; t < CH; t += T) lds[t] = 0.f;
    __syncthreads();
    const int s0 = binStart[p];
    const int size = binStart[p + 1] - s0;
    const int a   = s0 + (int)((long)g * size / G);
    const int bnd = s0 + (int)((long)(g + 1) * size / G);
    for (int i = a + threadIdx.x; i < bnd; i += T)
        atomicAdd(&lds[binned[i] & (CH - 1)], 1.0f);
    __syncthreads();
    const int lo = p * CH;
    const int lim = min(CH, n - lo);
    float* outp = copies + (size_t)g * n + lo;
    for (int t = threadIdx.x; t < lim; t += T) outp[t] = lds[t];
}

// weighted scatter over bin p, slice g: lds[localdst] += v[src]
__global__ void k_sct_bin(const unsigned* __restrict__ binned, const int* __restrict__ binStart,
                          int G, const float* __restrict__ v,
                          float* __restrict__ copies, int n) {
    const int g = blockIdx.x % G;
    const int p = blockIdx.x / G;
    __shared__ float lds[CH];
    for (int t = threadIdx.x; t < CH; t += T) lds[t] = 0.f;
    __syncthreads();
    const int s0 = binStart[p];
    const int size = binStart[p + 1] - s0;
    const int a   = s0 + (int)((long)g * size / G);
    const int bnd = s0 + (int)((long)(g + 1) * size / G);
    for (int i = a + threadIdx.x; i < bnd; i += T) {
        unsigned r = binned[i];
        atomicAdd(&lds[r & (CH - 1)], v[r >> 13]);
    }
    __syncthreads();
    const int lo = p * CH;
    const int lim = min(CH, n - lo);
    float* outp = copies + (size_t)g * n + lo;
    for (int t = threadIdx.x; t < lim; t += T) outp[t] = lds[t];
}

// ===================== fallback: round-5 LDS-partition path =====================

__global__ void k_cnt_part(const int* __restrict__ dst, int e, int G,
                           float* __restrict__ copies, int n) {
    const int g = blockIdx.x % G;
    const int p = blockIdx.x / G;
    __shared__ float lds[CH2];
    for (int t = threadIdx.x; t < CH2; t += T) lds[t] = 0.f;
    __syncthreads();
    const int lo = p * CH2;
    const int nv4 = e >> 2;
    const long s4 = (long)g * nv4 / G;
    const long e4 = (long)(g + 1) * nv4 / G;
    const int4* d4 = (const int4*)dst;
    for (long i = s4 + threadIdx.x; i < e4; i += T) {
        int4 d = d4[i];
        if ((unsigned)(d.x - lo) < (unsigned)CH2) atomicAdd(&lds[d.x - lo], 1.f);
        if ((unsigned)(d.y - lo) < (unsigned)CH2) atomicAdd(&lds[d.y - lo], 1.f);
        if ((unsigned)(d.z - lo) < (unsigned)CH2) atomicAdd(&lds[d.z - lo], 1.f);
        if ((unsigned)(d.w - lo) < (unsigned)CH2) atomicAdd(&lds[d.w - lo], 1.f);
    }
    if (g == G - 1) {
        for (int j = (nv4 << 2) + threadIdx.x; j < e; j += T) {
            int d = dst[j];
            if ((unsigned)(d - lo) < (unsigned)CH2) atomicAdd(&lds[d - lo], 1.f);
        }
    }
    __syncthreads();
    const int lim = min(CH2, n - lo);
    float* outp = copies + (size_t)g * n + lo;
    for (int t = threadIdx.x; t < lim; t += T) outp[t] = lds[t];
}

__global__ void k_sct_part(const int* __restrict__ src, const int* __restrict__ dst,
                           const float* __restrict__ v, int e, int G,
                           float* __restrict__ copies, int n) {
    const int g = blockIdx.x % G;
    const int p = blockIdx.x / G;
    __shared__ float lds[CH2];
    for (int t = threadIdx.x; t < CH2; t += T) lds[t] = 0.f;
    __syncthreads();
    const int lo = p * CH2;
    const int nv4 = e >> 2;
    const long s4 = (long)g * nv4 / G;
    const long e4 = (long)(g + 1) * nv4 / G;
    const int4* d4 = (const int4*)dst;
    const int4* s4p = (const int4*)src;
    for (long i = s4 + threadIdx.x; i < e4; i += T) {
        int4 d = d4[i];
        int4 s = s4p[i];
        if ((unsigned)(d.x - lo) < (unsigned)CH2) atomicAdd(&lds[d.x - lo], v[s.x]);
        if ((unsigned)(d.y - lo) < (unsigned)CH2) atomicAdd(&lds[d.y - lo], v[s.y]);
        if ((unsigned)(d.z - lo) < (unsigned)CH2) atomicAdd(&lds[d.z - lo], v[s.z]);
        if ((unsigned)(d.w - lo) < (unsigned)CH2) atomicAdd(&lds[d.w - lo], v[s.w]);
    }
    if (g == G - 1) {
        for (int j = (nv4 << 2) + threadIdx.x; j < e; j += T) {
            int d = dst[j];
            if ((unsigned)(d - lo) < (unsigned)CH2) atomicAdd(&lds[d - lo], v[src[j]]);
        }
    }
    __syncthreads();
    const int lim = min(CH2, n - lo);
    float* outp = copies + (size_t)g * n + lo;
    for (int t = threadIdx.x; t < lim; t += T) outp[t] = lds[t];
}

// ===================== fallback: global-atomic path (round-4) =====================

__global__ void k_zero(float* __restrict__ c, int total) {
    int nvec = total >> 2;
    float4* c4 = (float4*)c;
    int i = blockIdx.x * blockDim.x + threadIdx.x;
    int stride = gridDim.x * blockDim.x;
    float4 z = {0.f, 0.f, 0.f, 0.f};
    for (int j = i; j < nvec; j += stride) c4[j] = z;
    if (i < (total & 3)) c[(nvec << 2) + i] = 0.f;
}

__global__ void k_count_atomic(const int* __restrict__ dst, int e,
                               float* __restrict__ copies, int n, int kmask) {
    float* c = copies + (size_t)(blockIdx.x & kmask) * n;
    int i = blockIdx.x * blockDim.x + threadIdx.x;
    int base = i * 4;
    if (base + 4 <= e) {
        int4 d = *reinterpret_cast<const int4*>(dst + base);
        unsafeAtomicAdd(&c[d.x], 1.0f);
        unsafeAtomicAdd(&c[d.y], 1.0f);
        unsafeAtomicAdd(&c[d.z], 1.0f);
        unsafeAtomicAdd(&c[d.w], 1.0f);
    } else {
        for (int j = base; j < e; ++j) unsafeAtomicAdd(&c[dst[j]], 1.0f);
    }
}

__global__ void k_scatter_atomic(const int* __restrict__ src, const int* __restrict__ dst,
                                 const float* __restrict__ v,
                                 float* __restrict__ copies, int n, int kmask, int e) {
    float* c = copies + (size_t)(blockIdx.x & kmask) * n;
    int i = blockIdx.x * blockDim.x + threadIdx.x;
    int base = i * 4;
    if (base + 4 <= e) {
        int4 s = *reinterpret_cast<const int4*>(src + base);
        int4 d = *reinterpret_cast<const int4*>(dst + base);
        float vx = v[s.x], vy = v[s.y], vz = v[s.z], vw = v[s.w];
        unsafeAtomicAdd(&c[d.x], vx);
        unsafeAtomicAdd(&c[d.y], vy);
        unsafeAtomicAdd(&c[d.z], vz);
        unsafeAtomicAdd(&c[d.w], vw);
    } else {
        for (int j = base; j < e; ++j) unsafeAtomicAdd(&c[dst[j]], v[src[j]]);
    }
}

// ===================== node-side combine kernels (shared) =====================

__global__ void k_node1(const float* __restrict__ x, float* __restrict__ copies,
                        float* __restrict__ dinv, float* __restrict__ p,
                        int n, int K, int rz) {
    int i = blockIdx.x * blockDim.x + threadIdx.x;
    if (i < n) {
        float s = 1.0f;  // self-loop
        for (int k = 0; k < K; ++k) {
            s += copies[(size_t)k * n + i];
            if (rz) copies[(size_t)k * n + i] = 0.f;
        }
        float dv = rsqrtf(s);
        dinv[i] = dv;
        p[i] = dv * x[i];
    }
}

__global__ void k_node2(const float* __restrict__ dinv, const float* __restrict__ p,
                        float* __restrict__ copies,
                        const float* __restrict__ W1, const float* __restrict__ b1,
                        const float* __restrict__ W2,
                        float* __restrict__ q, int n, int K, int rz) {
    int i = blockIdx.x * blockDim.x + threadIdx.x;
    if (i < n) {
        float t1 = p[i];
        for (int k = 0; k < K; ++k) {
            t1 += copies[(size_t)k * n + i];
            if (rz) copies[(size_t)k * n + i] = 0.f;
        }
        float dv = dinv[i];
        float u = dv * t1;
        float h2 = 0.0f;
#pragma unroll
        for (int f = 0; f < 16; ++f) {
            float h = fmaxf(fmaf(u, W1[f], b1[f]), 0.0f);
            h2 = fmaf(h, W2[f], h2);
        }
        q[i] = dv * h2;
    }
}

__global__ void k_out(const float* __restrict__ dinv, const float* __restrict__ q,
                      const float* __restrict__ copies,
                      const float* __restrict__ b2, float* __restrict__ out, int n, int K) {
    int i = blockIdx.x * blockDim.x + threadIdx.x;
    if (i < n) {
        float t2 = q[i];
        for (int k = 0; k < K; ++k) t2 += copies[(size_t)k * n + i];
        out[i] = fmaf(dinv[i], t2, b2[0]);
    }
}

// ==============================================================================

extern "C" void kernel_launch(void* const* d_in, const int* in_sizes, int n_in,
                              void* d_out, int out_size, void* d_ws, size_t ws_size,
                              hipStream_t stream) {
    const float* x  = (const float*)d_in[0];
    const float* W1 = (const float*)d_in[1];
    const float* b1 = (const float*)d_in[2];
    const float* W2 = (const float*)d_in[3];
    const float* b2 = (const float*)d_in[4];
    const int*   ei = (const int*)d_in[5];   // [2, E] int32

    const int n = in_sizes[0];        // 100000
    const int e = in_sizes[5] / 2;    // 3200000
    const int* src = ei;
    const int* dst = ei + e;

    float* out = (float*)d_out;
    const int nb_n = (n + T - 1) / T;
    const size_t units = ws_size / 4;

    // ---- binned-path workspace layout ----
    float* dinv = (float*)d_ws;
    float* p    = dinv + n;
    float* q    = p + n;
    int* binStart = (int*)(q + n);                 // PMAX+1
    int* cursor   = binStart + (PMAX + 1);         // PMAX
    int* blockCnt = cursor + PMAX;                 // BB*PMAX
    unsigned* binned = (unsigned*)(blockCnt + (size_t)BB * PMAX);  // e
    float* copiesB = (float*)(binned + e);         // G*n

    long long fixedu = 3LL * n + (PMAX + 1) + PMAX + (long long)BB * PMAX + e;
    long long Gll = 0;
    if (n <= 131072 && (long long)units > fixedu)
        Gll = ((long long)units - fixedu) / n;
    int G = (int)(Gll > 48 ? 48 : Gll);
    const int P = (n + CH - 1) / CH;               // 13 for n=100000

    if (G >= 13 && P <= PMAX) {
        // =========== binned path ===========
        const int nbpg = P * G;
        k_binhist<<<BB, T, 0, stream>>>(dst, e, blockCnt);
        k_prefix<<<1, T, 0, stream>>>(blockCnt, P, cursor, binStart);
        k_binplace<<<BB, T, 0, stream>>>(src, dst, e, P, blockCnt, cursor, binned);
        k_cnt_bin<<<nbpg, T, 0, stream>>>(binned, binStart, G, copiesB, n);
        k_node1<<<nb_n, T, 0, stream>>>(x, copiesB, dinv, p, n, G, 0);
        k_sct_bin<<<nbpg, T, 0, stream>>>(binned, binStart, G, p, copiesB, n);
        k_node2<<<nb_n, T, 0, stream>>>(dinv, p, copiesB, W1, b1, W2, q, n, G, 0);
        k_sct_bin<<<nbpg, T, 0, stream>>>(binned, binStart, G, q, copiesB, n);
        k_out<<<nb_n, T, 0, stream>>>(dinv, q, copiesB, b2, out, n, G);
        return;
    }

    // ---- fallback layout (round-5): dinv, p, q, copies ----
    float* copies = q + n;
    long long avail = (long long)units - 3LL * n;
    int G2 = (int)(avail > 0 ? avail / n : 0);
    if (G2 > 64) G2 = 64;

    if (G2 >= 16) {
        const int P2 = (n + CH2 - 1) / CH2;
        const int nb_part = P2 * G2;
        k_cnt_part<<<nb_part, T, 0, stream>>>(dst, e, G2, copies, n);
        k_node1<<<nb_n, T, 0, stream>>>(x, copies, dinv, p, n, G2, 0);
        k_sct_part<<<nb_part, T, 0, stream>>>(src, dst, p, e, G2, copies, n);
        k_node2<<<nb_n, T, 0, stream>>>(dinv, p, copies, W1, b1, W2, q, n, G2, 0);
        k_sct_part<<<nb_part, T, 0, stream>>>(src, dst, q, e, G2, copies, n);
        k_out<<<nb_n, T, 0, stream>>>(dinv, q, copies, b2, out, n, G2);
    } else {
        int K = 1;
        while (K * 2 <= 8 && (long long)(K * 2) * n <= avail) K *= 2;
        const int kmask = K - 1;
        const int e4   = (e + 3) / 4;
        const int nb_e = (e4 + T - 1) / T;
        const int nb_z = min(((K * n / 4) + T - 1) / T, 2048);

        k_zero<<<nb_z, T, 0, stream>>>(copies, K * n);
        k_count_atomic<<<nb_e, T, 0, stream>>>(dst, e, copies, n, kmask);
        k_node1<<<nb_n, T, 0, stream>>>(x, copies, dinv, p, n, K, 1);
        k_scatter_atomic<<<nb_e, T, 0, stream>>>(src, dst, p, copies, n, kmask, e);
        k_node2<<<nb_n, T, 0, stream>>>(dinv, p, copies, W1, b1, W2, q, n, K, 1);
        k_scatter_atomic<<<nb_e, T, 0, stream>>>(src, dst, q, copies, n, kmask, e);
        k_out<<<nb_n, T, 0, stream>>>(dinv, q, copies, b2, out, n, K);
    }
}